// Round 19
// baseline (136.262 us; speedup 1.0000x reference)
//
#include <hip/hip_runtime.h>

constexpr int N_NODES = 50000;
constexpr int N_EDGES = 800000;
constexpr int IN_F = 64;
constexpr int ED_F = 16;
constexpr int OUT_F = 64;
constexpr int AGG_F = 256;    // 4*IN
constexpr int KTOT = 832;     // 13*64
constexpr float AVG_D_LOG_F = 2.833f;
constexpr float EPS_F = 1e-5f;

// binning geometry: 256 buckets x 196 nodes; bucket-strided spans of 4096
// bucket counts ~ Binom(800K, 196/50176) = 3136 +/- 56 ; 4096 is ~17 sigma -> safe
constexpr int NB_BKT = 256;
constexpr int NODES_PER_BKT = 196;
constexpr int BKT_STRIDE = 4096;
constexpr int EPB_C = 4096;                                   // edges per binC block
constexpr int NBLK_C = (N_EDGES + EPB_C - 1) / EPB_C;         // 196

// aggmm: 4 nodes per wave
constexpr int AGG_WAVES = 12500;        // 50000 / 4
constexpr int AGG_BLOCKS = AGG_WAVES / 4;   // 3125

typedef __attribute__((ext_vector_type(8))) short short8;
typedef __attribute__((ext_vector_type(4))) float f32x4;

__device__ __forceinline__ int rfl(int v) { return __builtin_amdgcn_readfirstlane(v); }
__device__ __forceinline__ unsigned short f2bf(float f) {   // RNE f32->bf16
    unsigned u = __float_as_uint(f);
    unsigned r = (u + 0x7FFFu + ((u >> 16) & 1u)) >> 16;
    return (unsigned short)r;
}

// ---------------- fused prep: p12 MFMA + ef conversion + W prep (hist REMOVED) ----------------
constexpr int P12MM_BLKS = 625;
constexpr int P12_TPB = 5;
constexpr int CONV_BLKS = 2500;
__global__ __launch_bounds__(256) void prep_kernel(
    const float* __restrict__ h, const float* __restrict__ Wpre, const float* __restrict__ bpre,
    const float* __restrict__ ef, const float* __restrict__ Wpost,
    unsigned short* __restrict__ P1b, float* __restrict__ P2, unsigned short* __restrict__ hb,
    unsigned short* __restrict__ efb,
    unsigned short* __restrict__ WT, unsigned short* __restrict__ WefT)
{
    int tid = threadIdx.x;
    if (blockIdx.x < P12MM_BLKS) {
        int lane = tid & 63;
        int li = lane & 15;
        int lg = lane >> 4;
        int w = tid >> 6;
        int col = w * 16 + li;

        short8 B1[2], B2[2];
        #pragma unroll
        for (int s = 0; s < 2; ++s) {
            short8 b1 = {}, b2 = {};
            #pragma unroll
            for (int j = 0; j < 8; ++j) {
                int k = s * 32 + (lg << 3) + j;
                b1[j] = (short)f2bf(Wpre[k * 64 + col]);
                b2[j] = (short)f2bf(Wpre[(64 + k) * 64 + col]);
            }
            B1[s] = b1; B2[s] = b2;
        }
        float bj = bpre[col];

        #pragma unroll 1
        for (int t = 0; t < P12_TPB; ++t) {
            int tile = blockIdx.x + t * P12MM_BLKS;
            int nA = tile * 16 + li;
            const float* hrow = h + (size_t)nA * IN_F;
            float4 v0 = *reinterpret_cast<const float4*>(hrow + (lg << 3));
            float4 v1 = *reinterpret_cast<const float4*>(hrow + (lg << 3) + 4);
            float4 v2 = *reinterpret_cast<const float4*>(hrow + 32 + (lg << 3));
            float4 v3 = *reinterpret_cast<const float4*>(hrow + 32 + (lg << 3) + 4);
            short8 a0, a1;
            a0[0]=(short)f2bf(v0.x); a0[1]=(short)f2bf(v0.y); a0[2]=(short)f2bf(v0.z); a0[3]=(short)f2bf(v0.w);
            a0[4]=(short)f2bf(v1.x); a0[5]=(short)f2bf(v1.y); a0[6]=(short)f2bf(v1.z); a0[7]=(short)f2bf(v1.w);
            a1[0]=(short)f2bf(v2.x); a1[1]=(short)f2bf(v2.y); a1[2]=(short)f2bf(v2.z); a1[3]=(short)f2bf(v2.w);
            a1[4]=(short)f2bf(v3.x); a1[5]=(short)f2bf(v3.y); a1[6]=(short)f2bf(v3.z); a1[7]=(short)f2bf(v3.w);

            if (w == 0) {
                *reinterpret_cast<short8*>(hb + (size_t)nA * IN_F + (lg << 3)) = a0;
                *reinterpret_cast<short8*>(hb + (size_t)nA * IN_F + 32 + (lg << 3)) = a1;
            }

            f32x4 p1a = {0.f,0.f,0.f,0.f}, p2a = {0.f,0.f,0.f,0.f};
            p1a = __builtin_amdgcn_mfma_f32_16x16x32_bf16(a0, B1[0], p1a, 0, 0, 0);
            p1a = __builtin_amdgcn_mfma_f32_16x16x32_bf16(a1, B1[1], p1a, 0, 0, 0);
            p2a = __builtin_amdgcn_mfma_f32_16x16x32_bf16(a0, B2[0], p2a, 0, 0, 0);
            p2a = __builtin_amdgcn_mfma_f32_16x16x32_bf16(a1, B2[1], p2a, 0, 0, 0);

            #pragma unroll
            for (int rr = 0; rr < 4; ++rr) {
                int node = tile * 16 + (lg << 2) + rr;
                P1b[(size_t)node * IN_F + col] = f2bf(p1a[rr]);
                P2[(size_t)node * IN_F + col] = p2a[rr] + bj;
            }
        }
    } else {
        int cgid = (blockIdx.x - P12MM_BLKS) * 256 + tid;
        const float4* ef4 = reinterpret_cast<const float4*>(ef);
        #pragma unroll
        for (int k = 0; k < 5; ++k) {
            int i = cgid + k * (CONV_BLKS * 256);
            float4 v = ef4[i];
            ushort4 o;
            o.x = f2bf(v.x); o.y = f2bf(v.y); o.z = f2bf(v.z); o.w = f2bf(v.w);
            *reinterpret_cast<ushort4*>(efb + (size_t)i * 4) = o;
        }
        if (cgid < OUT_F * KTOT) {
            int n = cgid / KTOT, k = cgid % KTOT;
            WT[cgid] = f2bf(Wpost[(size_t)k * OUT_F + n]);
        }
        if (cgid < 64 * 16) {
            int n = cgid >> 4, k = cgid & 15;
            WefT[cgid] = f2bf(Wpre[(128 + k) * 64 + n]);
        }
    }
}

// ---------------- binC: counting-sort into BUCKET-STRIDED staging (no prior scan) ----------------
__global__ __launch_bounds__(256) void binC_kernel(
    const int* __restrict__ src, const int* __restrict__ dst, int* __restrict__ bcur0,
    int* __restrict__ stage_e, int* __restrict__ stage_sd)
{
    __shared__ int sL[EPB_C];
    __shared__ int dL[EPB_C];
    __shared__ int bh[NB_BKT];
    __shared__ int bbase[NB_BKT];
    __shared__ int bcsr[NB_BKT];

    int tid = threadIdx.x;
    int e0 = blockIdx.x * EPB_C;

    bh[tid] = 0;
    __syncthreads();
    #pragma unroll
    for (int k = 0; k < EPB_C / 256; ++k) {
        int t = k * 256 + tid;
        int e = e0 + t;
        if (e < N_EDGES) {
            int s = src[e], d = dst[e];
            sL[t] = s; dL[t] = d;
            atomicAdd(&bh[d / NODES_PER_BKT], 1);
        }
    }
    __syncthreads();
    // claim contiguous run within the bucket's private span (cursor starts at 0)
    bbase[tid] = (bh[tid] > 0) ? atomicAdd(&bcur0[tid], bh[tid]) : 0;
    bcsr[tid] = 0;
    __syncthreads();
    #pragma unroll
    for (int k = 0; k < EPB_C / 256; ++k) {
        int t = k * 256 + tid;
        int e = e0 + t;
        if (e < N_EDGES) {
            int d = dL[t];
            int b = d / NODES_PER_BKT;
            int dl = d - b * NODES_PER_BKT;
            int r = atomicAdd(&bcsr[b], 1);
            int pos = (b << 12) + bbase[b] + r;     // bucket-strided
            stage_e[pos] = e;
            stage_sd[pos] = sL[t] | (dl << 16);
        }
    }
}

// ---------------- binD: per-bucket deg/row_start (LDS scan) + fine scatter, strided ----------------
__global__ __launch_bounds__(256) void binD_kernel(
    const int* __restrict__ stage_e, const int* __restrict__ stage_sd,
    const int* __restrict__ bcur0,
    int* __restrict__ deg, int* __restrict__ row_start, int2* __restrict__ csr2)
{
    __shared__ int cnt[NB_BKT];
    __shared__ int lofs[NODES_PER_BKT];
    __shared__ int ws[4];
    int tid = threadIdx.x, lane = tid & 63, wv = tid >> 6;
    int b = blockIdx.x;
    int nb0 = b * NODES_PER_BKT;
    int base = b << 12;
    cnt[tid] = 0;
    __syncthreads();
    int cntb = bcur0[b];
    for (int p = base + tid; p < base + cntb; p += 256)
        atomicAdd(&cnt[stage_sd[p] >> 16], 1);
    __syncthreads();
    int v = cnt[tid];
    int sc = v;
    #pragma unroll
    for (int off = 1; off < 64; off <<= 1) {
        int u = __shfl_up(sc, off);
        if (lane >= off) sc += u;
    }
    if (lane == 63) ws[wv] = sc;
    __syncthreads();
    int wbase = 0;
    #pragma unroll
    for (int w = 0; w < 4; ++w) if (w < wv) wbase += ws[w];
    int ex = wbase + sc - v;
    if (tid < NODES_PER_BKT) {
        int n = nb0 + tid;
        if (n < N_NODES) { deg[n] = v; row_start[n] = base + ex; }
        lofs[tid] = base + ex;
    }
    __syncthreads();
    for (int p = base + tid; p < base + cntb; p += 256) {
        int sd = stage_sd[p];
        int r = atomicAdd(&lofs[sd >> 16], 1);
        csr2[r] = make_int2(stage_e[p], sd & 0xFFFF);
    }
}

// ---------------- aggmm helpers ----------------
#define AGG_MFMA8(aP0_, aP1_, aE_) \
    c0 = __builtin_amdgcn_mfma_f32_16x16x32_bf16(aP0_, bI0, c0, 0, 0, 0); \
    c1 = __builtin_amdgcn_mfma_f32_16x16x32_bf16(aP0_, bI1, c1, 0, 0, 0); \
    c2 = __builtin_amdgcn_mfma_f32_16x16x32_bf16(aP1_, bI0, c2, 0, 0, 0); \
    c3 = __builtin_amdgcn_mfma_f32_16x16x32_bf16(aP1_, bI1, c3, 0, 0, 0); \
    c0 = __builtin_amdgcn_mfma_f32_16x16x32_bf16(aE_, bE0, c0, 0, 0, 0);  \
    c1 = __builtin_amdgcn_mfma_f32_16x16x32_bf16(aE_, bE1, c1, 0, 0, 0);  \
    c2 = __builtin_amdgcn_mfma_f32_16x16x32_bf16(aE_, bE2, c2, 0, 0, 0);  \
    c3 = __builtin_amdgcn_mfma_f32_16x16x32_bf16(aE_, bE3, c3, 0, 0, 0);

#define STATS_FULL() do { \
    sm[0] += (c0[0] + c0[1]) + (c0[2] + c0[3]); \
    sm[1] += (c1[0] + c1[1]) + (c1[2] + c1[3]); \
    sm[2] += (c2[0] + c2[1]) + (c2[2] + c2[3]); \
    sm[3] += (c3[0] + c3[1]) + (c3[2] + c3[3]); \
    sq[0] = fmaf(c0[0],c0[0], fmaf(c0[1],c0[1], fmaf(c0[2],c0[2], fmaf(c0[3],c0[3], sq[0])))); \
    sq[1] = fmaf(c1[0],c1[0], fmaf(c1[1],c1[1], fmaf(c1[2],c1[2], fmaf(c1[3],c1[3], sq[1])))); \
    sq[2] = fmaf(c2[0],c2[0], fmaf(c2[1],c2[1], fmaf(c2[2],c2[2], fmaf(c2[3],c2[3], sq[2])))); \
    sq[3] = fmaf(c3[0],c3[0], fmaf(c3[1],c3[1], fmaf(c3[2],c3[2], fmaf(c3[3],c3[3], sq[3])))); \
    mx[0] = fmaxf(fmaxf(fmaxf(fmaxf(mx[0], c0[0]), c0[1]), c0[2]), c0[3]); \
    mx[1] = fmaxf(fmaxf(fmaxf(fmaxf(mx[1], c1[0]), c1[1]), c1[2]), c1[3]); \
    mx[2] = fmaxf(fmaxf(fmaxf(fmaxf(mx[2], c2[0]), c2[1]), c2[2]), c2[3]); \
    mx[3] = fmaxf(fmaxf(fmaxf(fmaxf(mx[3], c3[0]), c3[1]), c3[2]), c3[3]); \
    mn[0] = fminf(fminf(fminf(fminf(mn[0], c0[0]), c0[1]), c0[2]), c0[3]); \
    mn[1] = fminf(fminf(fminf(fminf(mn[1], c1[0]), c1[1]), c1[2]), c1[3]); \
    mn[2] = fminf(fminf(fminf(fminf(mn[2], c2[0]), c2[1]), c2[2]), c2[3]); \
    mn[3] = fminf(fminf(fminf(fminf(mn[3], c3[0]), c3[1]), c3[2]), c3[3]); \
} while (0)

#define STATS_MASK(RB_, LIM_) do { \
    _Pragma("unroll") \
    for (int rr = 0; rr < 4; ++rr) { \
        bool vv = ((RB_) + rr) < (LIM_); \
        float x0 = c0[rr], x1 = c1[rr], x2 = c2[rr], x3 = c3[rr]; \
        float z0 = vv ? x0 : 0.f, z1 = vv ? x1 : 0.f, z2 = vv ? x2 : 0.f, z3 = vv ? x3 : 0.f; \
        sm[0] += z0; sm[1] += z1; sm[2] += z2; sm[3] += z3; \
        sq[0] = fmaf(z0, z0, sq[0]); sq[1] = fmaf(z1, z1, sq[1]); \
        sq[2] = fmaf(z2, z2, sq[2]); sq[3] = fmaf(z3, z3, sq[3]); \
        mx[0] = fmaxf(mx[0], x0); mx[1] = fmaxf(mx[1], x1); \
        mx[2] = fmaxf(mx[2], x2); mx[3] = fmaxf(mx[3], x3); \
        mn[0] = fminf(mn[0], x0); mn[1] = fminf(mn[1], x1); \
        mn[2] = fminf(mn[2], x2); mn[3] = fminf(mn[3], x3); \
    } \
} while (0)

// ---------------- aggregation: 4 nodes/wave, 2-stage gather pipeline ----------------
__global__ __launch_bounds__(256) void aggmm_kernel(
    const unsigned short* __restrict__ P1b, const float* __restrict__ P2,
    const unsigned short* __restrict__ efb, const unsigned short* __restrict__ WefT,
    const int2* __restrict__ csr2, const int* __restrict__ row_start,
    const int* __restrict__ deg, unsigned short* __restrict__ aggb)
{
    int tid = threadIdx.x;
    int lane = tid & 63;
    int lg = lane >> 4;
    int li = lane & 15;

    short8 bI0 = {}, bI1 = {};
    #pragma unroll
    for (int j = 0; j < 8; ++j) {
        int k_local = (lg << 3) + j;
        if (k_local == li)      bI0[j] = (short)0x3F80;
        if (k_local == 16 + li) bI1[j] = (short)0x3F80;
    }
    short8 bE0 = {}, bE1 = {}, bE2 = {}, bE3 = {};
    if (lane < 32) {
        bE0 = *reinterpret_cast<const short8*>(WefT + (size_t)(0 * 16 + li) * 16 + (lg << 3));
        bE1 = *reinterpret_cast<const short8*>(WefT + (size_t)(1 * 16 + li) * 16 + (lg << 3));
        bE2 = *reinterpret_cast<const short8*>(WefT + (size_t)(2 * 16 + li) * 16 + (lg << 3));
        bE3 = *reinterpret_cast<const short8*>(WefT + (size_t)(3 * 16 + li) * 16 + (lg << 3));
    }

    int wgid = rfl(blockIdx.x * 4 + (tid >> 6));    // 0..12499

    // ---- batch ALL independent per-node scalar/vector loads upfront ----
    int rsA[4], dgA[4];
    float p2A[4];
    #pragma unroll
    for (int nn = 0; nn < 4; ++nn) {
        int n = wgid + nn * AGG_WAVES;
        rsA[nn] = rfl(row_start[n]);
        dgA[nn] = rfl(deg[n]);
        p2A[nn] = P2[(size_t)n * IN_F + lane];
    }

    // index loads for nodes 0 and 1 (clamped; always-valid addresses within bucket span)
    int2 eA[4], eB[4];
    #pragma unroll
    for (int nn = 0; nn < 2; ++nn) {
        int dgc = dgA[nn] > 0 ? dgA[nn] : 1;
        int i0 = li < dgc ? li : dgc - 1;
        int i1 = 16 + li < dgc ? 16 + li : dgc - 1;
        eA[nn] = csr2[rsA[nn] + i0];
        eB[nn] = csr2[rsA[nn] + i1];
    }

    // prologue: gathers for node 0
    short8 gP0a, gP1a, gP0b, gP1b, gEa, gEb;
    {
        const unsigned short* pr0 = P1b + (size_t)eA[0].y * IN_F + (lg << 3);
        const unsigned short* pr1 = P1b + (size_t)eB[0].y * IN_F + (lg << 3);
        gP0a = *reinterpret_cast<const short8*>(pr0);
        gP1a = *reinterpret_cast<const short8*>(pr0 + 32);
        gP0b = *reinterpret_cast<const short8*>(pr1);
        gP1b = *reinterpret_cast<const short8*>(pr1 + 32);
        short8 z = {};
        gEa = z; gEb = z;
        if (lane < 32) {
            gEa = *reinterpret_cast<const short8*>(efb + (size_t)eA[0].x * ED_F + (lg << 3));
            gEb = *reinterpret_cast<const short8*>(efb + (size_t)eB[0].x * ED_F + (lg << 3));
        }
    }

    #pragma unroll
    for (int nn = 0; nn < 4; ++nn) {
        int n = wgid + nn * AGG_WAVES;
        int dg = dgA[nn];

        // take current gathers
        short8 aP0a = gP0a, aP1a = gP1a, aP0b = gP0b, aP1b = gP1b, aEa = gEa, aEb = gEb;

        // issue NEXT node's gathers now (indices were loaded >= 1 iteration ago)
        if (nn < 3) {
            const unsigned short* pr0 = P1b + (size_t)eA[nn + 1].y * IN_F + (lg << 3);
            const unsigned short* pr1 = P1b + (size_t)eB[nn + 1].y * IN_F + (lg << 3);
            gP0a = *reinterpret_cast<const short8*>(pr0);
            gP1a = *reinterpret_cast<const short8*>(pr0 + 32);
            gP0b = *reinterpret_cast<const short8*>(pr1);
            gP1b = *reinterpret_cast<const short8*>(pr1 + 32);
            short8 z = {};
            gEa = z; gEb = z;
            if (lane < 32) {
                gEa = *reinterpret_cast<const short8*>(efb + (size_t)eA[nn + 1].x * ED_F + (lg << 3));
                gEb = *reinterpret_cast<const short8*>(efb + (size_t)eB[nn + 1].x * ED_F + (lg << 3));
            }
        }
        // issue node nn+2's index loads
        if (nn < 2) {
            int m = nn + 2;
            int dgc = dgA[m] > 0 ? dgA[m] : 1;
            int i0 = li < dgc ? li : dgc - 1;
            int i1 = 16 + li < dgc ? 16 + li : dgc - 1;
            eA[m] = csr2[rsA[m] + i0];
            eB[m] = csr2[rsA[m] + i1];
        }

        size_t obase = (size_t)n * AGG_F + lane;
        if (dg == 0) {
            aggb[obase] = 0; aggb[obase + 64] = 0;
            aggb[obase + 128] = 0; aggb[obase + 192] = 0;
            continue;
        }

        float p2n = p2A[nn];
        const float NINF = -__builtin_inff(), PINF = __builtin_inff();
        float sm[4] = {0.f, 0.f, 0.f, 0.f};
        float sq[4] = {0.f, 0.f, 0.f, 0.f};
        float mx[4] = {NINF, NINF, NINF, NINF};
        float mn[4] = {PINF, PINF, PINF, PINF};

        if (dg <= 32) {
            {   // tile 0
                f32x4 c0 = {0.f,0.f,0.f,0.f}, c1 = {0.f,0.f,0.f,0.f};
                f32x4 c2 = {0.f,0.f,0.f,0.f}, c3 = {0.f,0.f,0.f,0.f};
                AGG_MFMA8(aP0a, aP1a, aEa);
                if (dg >= 16) { STATS_FULL(); }
                else          { STATS_MASK((lg << 2), dg); }
            }
            if (dg > 16) {   // tile 1 (wave-uniform)
                f32x4 c0 = {0.f,0.f,0.f,0.f}, c1 = {0.f,0.f,0.f,0.f};
                f32x4 c2 = {0.f,0.f,0.f,0.f}, c3 = {0.f,0.f,0.f,0.f};
                AGG_MFMA8(aP0b, aP1b, aEb);
                if (dg >= 32) { STATS_FULL(); }
                else          { STATS_MASK(16 + (lg << 2), dg); }
            }
        } else {
            // slow path (rare): chunked shfl walk, any dg
            for (int base = 0; base < dg; base += 64) {
                int cnt = dg - base; if (cnt > 64) cnt = 64;
                int2 es = make_int2(0, 0);
                if (lane < cnt) es = csr2[rsA[nn] + base + lane];
                int eid = es.x, sid = es.y;
                int nrt = (cnt + 15) >> 4;
                for (int rt = 0; rt < nrt; ++rt) {
                    int srcidx = rt * 16 + li;
                    if (srcidx >= cnt) srcidx = cnt - 1;
                    int s_l = __shfl(sid, srcidx);
                    int e_l = __shfl(eid, srcidx);
                    short8 aP0 = *reinterpret_cast<const short8*>(P1b + (size_t)s_l * IN_F + (lg << 3));
                    short8 aP1 = *reinterpret_cast<const short8*>(P1b + (size_t)s_l * IN_F + 32 + (lg << 3));
                    short8 aE = {};
                    if (lane < 32)
                        aE = *reinterpret_cast<const short8*>(efb + (size_t)e_l * ED_F + (lg << 3));
                    f32x4 c0 = {0.f,0.f,0.f,0.f}, c1 = {0.f,0.f,0.f,0.f};
                    f32x4 c2 = {0.f,0.f,0.f,0.f}, c3 = {0.f,0.f,0.f,0.f};
                    AGG_MFMA8(aP0, aP1, aE);
                    int rb2 = rt * 16 + (lg << 2);
                    STATS_MASK(rb2, cnt);
                }
            }
        }

        // butterfly over lane groups
        #pragma unroll
        for (int ct = 0; ct < 4; ++ct) {
            #pragma unroll
            for (int off = 16; off <= 32; off <<= 1) {
                sm[ct] += __shfl_xor(sm[ct], off);
                sq[ct] += __shfl_xor(sq[ct], off);
                mx[ct] = fmaxf(mx[ct], __shfl_xor(mx[ct], off));
                mn[ct] = fminf(mn[ct], __shfl_xor(mn[ct], off));
            }
        }
        bool s16 = (lane & 16) != 0, s32 = (lane & 32) != 0;
        float S  = s32 ? (s16 ? sm[3] : sm[2]) : (s16 ? sm[1] : sm[0]);
        float Qq = s32 ? (s16 ? sq[3] : sq[2]) : (s16 ? sq[1] : sq[0]);
        float MX = s32 ? (s16 ? mx[3] : mx[2]) : (s16 ? mx[1] : mx[0]);
        float MN = s32 ? (s16 ? mn[3] : mn[2]) : (s16 ? mn[1] : mn[0]);

        float degc = (float)dg;
        float mean_x = S / degc;
        float sd = sqrtf(fmaxf(Qq / degc - mean_x * mean_x, 0.f) + EPS_F);
        aggb[obase]       = f2bf(mean_x + p2n);
        aggb[obase + 64]  = f2bf(MX + p2n);
        aggb[obase + 128] = f2bf(MN + p2n);
        aggb[obase + 192] = f2bf(sd);
    }
}

// ---------------- MFMA post, persistent-B (unchanged R12) ----------------
constexpr int POST_BLOCKS = 625;
constexpr int TILES_PER_BLOCK = 5;
__global__ __launch_bounds__(256, 2) void postmm_kernel(
    const unsigned short* __restrict__ hb, const float* __restrict__ snorm,
    const unsigned short* __restrict__ WT, const float* __restrict__ bpost,
    const unsigned short* __restrict__ aggb, const int* __restrict__ deg,
    float* __restrict__ out)
{
    int tid = threadIdx.x;
    int lane = tid & 63;
    int li = lane & 15;
    int lg = lane >> 4;
    int w = tid >> 6;

    const unsigned short* Brow = WT + (size_t)(w * 16 + li) * KTOT + (lg << 3);
    short8 B[26];
    #pragma unroll
    for (int s = 0; s < 26; ++s)
        B[s] = *reinterpret_cast<const short8*>(Brow + s * 32);

    float bp = bpost[w * 16 + li];

    #pragma unroll 1
    for (int t = 0; t < TILES_PER_BLOCK; ++t) {
        int tile = blockIdx.x + t * POST_BLOCKS;
        int nA = tile * 16 + li;
        const unsigned short* Ah = hb + (size_t)nA * IN_F + (lg << 3);
        const unsigned short* Ag = aggb + (size_t)nA * AGG_F + (lg << 3);

        short8 ah0 = *reinterpret_cast<const short8*>(Ah);
        short8 ah1 = *reinterpret_cast<const short8*>(Ah + 32);
        short8 ag[8];
        #pragma unroll
        for (int s = 0; s < 8; ++s)
            ag[s] = *reinterpret_cast<const short8*>(Ag + s * 32);

        f32x4 accA = {0.f,0.f,0.f,0.f}, accB = {0.f,0.f,0.f,0.f}, accC = {0.f,0.f,0.f,0.f};
        accA = __builtin_amdgcn_mfma_f32_16x16x32_bf16(ah0, B[0], accA, 0, 0, 0);
        accA = __builtin_amdgcn_mfma_f32_16x16x32_bf16(ah1, B[1], accA, 0, 0, 0);
        #pragma unroll
        for (int s = 0; s < 8; ++s) {
            accA = __builtin_amdgcn_mfma_f32_16x16x32_bf16(ag[s], B[2 + s],  accA, 0, 0, 0);
            accB = __builtin_amdgcn_mfma_f32_16x16x32_bf16(ag[s], B[10 + s], accB, 0, 0, 0);
            accC = __builtin_amdgcn_mfma_f32_16x16x32_bf16(ag[s], B[18 + s], accC, 0, 0, 0);
        }

        #pragma unroll
        for (int rr = 0; rr < 4; ++rr) {
            int node = tile * 16 + (lg << 2) + rr;
            int dg = deg[node];
            float degc = fmaxf((float)dg, 1.f);
            float logd = logf(degc + 1.f);
            float aR = logd * (1.f / AVG_D_LOG_F);
            float bR = AVG_D_LOG_F / logd;
            float v = accA[rr] + aR * accB[rr] + bR * accC[rr] + bp;
            out[(size_t)node * OUT_F + w * 16 + li] = v * snorm[node];
        }
    }
}

extern "C" void kernel_launch(void* const* d_in, const int* in_sizes, int n_in,
                              void* d_out, int out_size, void* d_ws, size_t ws_size,
                              hipStream_t stream) {
    const float* h     = (const float*)d_in[0];
    const float* ef    = (const float*)d_in[1];
    const float* snorm = (const float*)d_in[2];
    const float* Wpre  = (const float*)d_in[3];
    const float* bpre  = (const float*)d_in[4];
    const float* Wpost = (const float*)d_in[5];
    const float* bpost = (const float*)d_in[6];
    const int* src     = (const int*)d_in[7];
    const int* dst     = (const int*)d_in[8];
    float* out = (float*)d_out;

    char* ws = (char*)d_ws;
    size_t off = 0;
    auto alloc = [&](size_t bytes) { char* p = ws + off; off += (bytes + 255) & ~size_t(255); return p; };
    unsigned short* P1b  = (unsigned short*)alloc((size_t)N_NODES * IN_F * 2);       // 6.4 MB
    float* P2            = (float*)alloc((size_t)N_NODES * IN_F * 4);                // 12.8 MB
    unsigned short* hb   = (unsigned short*)alloc((size_t)N_NODES * IN_F * 2);       // 6.4 MB
    unsigned short* aggb = (unsigned short*)alloc((size_t)N_NODES * AGG_F * 2);      // 25.6 MB
    unsigned short* efb  = (unsigned short*)alloc((size_t)N_EDGES * ED_F * 2);       // 25.6 MB
    int* deg       = (int*)alloc((size_t)N_NODES * 4);
    int* row_start = (int*)alloc((size_t)N_NODES * 4);
    int2* csr2     = (int2*)alloc((size_t)NB_BKT * BKT_STRIDE * 8);                  // 8.4 MB
    int* stage_e   = (int*)alloc((size_t)NB_BKT * BKT_STRIDE * 4);                   // 4.2 MB
    int* stage_sd  = (int*)alloc((size_t)NB_BKT * BKT_STRIDE * 4);                   // 4.2 MB
    int* bcur0     = (int*)alloc((size_t)NB_BKT * 4);
    unsigned short* WT   = (unsigned short*)alloc((size_t)OUT_F * KTOT * 2);
    unsigned short* WefT = (unsigned short*)alloc((size_t)64 * 16 * 2);

    hipMemsetAsync(bcur0, 0, (size_t)NB_BKT * 4, stream);
    hipLaunchKernelGGL(prep_kernel, dim3(P12MM_BLKS + CONV_BLKS), dim3(256), 0, stream,
                       h, Wpre, bpre, ef, Wpost,
                       P1b, P2, hb, efb, WT, WefT);
    hipLaunchKernelGGL(binC_kernel, dim3(NBLK_C), dim3(256), 0, stream,
                       src, dst, bcur0, stage_e, stage_sd);
    hipLaunchKernelGGL(binD_kernel, dim3(NB_BKT), dim3(256), 0, stream,
                       stage_e, stage_sd, bcur0, deg, row_start, csr2);
    hipLaunchKernelGGL(aggmm_kernel, dim3(AGG_BLOCKS), dim3(256), 0, stream,
                       P1b, P2, efb, WefT, csr2, row_start, deg, aggb);
    hipLaunchKernelGGL(postmm_kernel, dim3(POST_BLOCKS), dim3(256), 0, stream,
                       hb, snorm, WT, bpost, aggb, deg, out);
}

// Round 20
// 127.623 us; speedup vs baseline: 1.0677x; 1.0677x over previous
//
#include <hip/hip_runtime.h>

constexpr int N_NODES = 50000;
constexpr int N_EDGES = 800000;
constexpr int IN_F = 64;
constexpr int ED_F = 16;
constexpr int OUT_F = 64;
constexpr int AGG_F = 256;    // 4*IN
constexpr int KTOT = 832;     // 13*64
constexpr float AVG_D_LOG_F = 2.833f;
constexpr float EPS_F = 1e-5f;

// binning geometry: 256 buckets x 196 nodes; bucket-strided spans of 4096
constexpr int NB_BKT = 256;
constexpr int NODES_PER_BKT = 196;
constexpr int BKT_STRIDE = 4096;
constexpr int EPB_C = 4096;
constexpr int NBLK_C = (N_EDGES + EPB_C - 1) / EPB_C;         // 196

// aggmm: 4 nodes per wave
constexpr int AGG_WAVES = 12500;        // 50000 / 4
constexpr int AGG_BLOCKS = AGG_WAVES / 4;   // 3125

typedef __attribute__((ext_vector_type(8))) short short8;
typedef __attribute__((ext_vector_type(4))) float f32x4;

__device__ __forceinline__ int rfl(int v) { return __builtin_amdgcn_readfirstlane(v); }
__device__ __forceinline__ unsigned short f2bf(float f) {   // RNE f32->bf16
    unsigned u = __float_as_uint(f);
    unsigned r = (u + 0x7FFFu + ((u >> 16) & 1u)) >> 16;
    return (unsigned short)r;
}

// ---------------- fused prep: p12 MFMA + ef conversion + W prep ----------------
constexpr int P12MM_BLKS = 625;
constexpr int P12_TPB = 5;
constexpr int CONV_BLKS = 2500;
__global__ __launch_bounds__(256) void prep_kernel(
    const float* __restrict__ h, const float* __restrict__ Wpre, const float* __restrict__ bpre,
    const float* __restrict__ ef, const float* __restrict__ Wpost,
    unsigned short* __restrict__ P1b, float* __restrict__ P2, unsigned short* __restrict__ hb,
    unsigned short* __restrict__ efb,
    unsigned short* __restrict__ WT, unsigned short* __restrict__ WefT)
{
    int tid = threadIdx.x;
    if (blockIdx.x < P12MM_BLKS) {
        int lane = tid & 63;
        int li = lane & 15;
        int lg = lane >> 4;
        int w = tid >> 6;
        int col = w * 16 + li;

        short8 B1[2], B2[2];
        #pragma unroll
        for (int s = 0; s < 2; ++s) {
            short8 b1 = {}, b2 = {};
            #pragma unroll
            for (int j = 0; j < 8; ++j) {
                int k = s * 32 + (lg << 3) + j;
                b1[j] = (short)f2bf(Wpre[k * 64 + col]);
                b2[j] = (short)f2bf(Wpre[(64 + k) * 64 + col]);
            }
            B1[s] = b1; B2[s] = b2;
        }
        float bj = bpre[col];

        #pragma unroll 1
        for (int t = 0; t < P12_TPB; ++t) {
            int tile = blockIdx.x + t * P12MM_BLKS;
            int nA = tile * 16 + li;
            const float* hrow = h + (size_t)nA * IN_F;
            float4 v0 = *reinterpret_cast<const float4*>(hrow + (lg << 3));
            float4 v1 = *reinterpret_cast<const float4*>(hrow + (lg << 3) + 4);
            float4 v2 = *reinterpret_cast<const float4*>(hrow + 32 + (lg << 3));
            float4 v3 = *reinterpret_cast<const float4*>(hrow + 32 + (lg << 3) + 4);
            short8 a0, a1;
            a0[0]=(short)f2bf(v0.x); a0[1]=(short)f2bf(v0.y); a0[2]=(short)f2bf(v0.z); a0[3]=(short)f2bf(v0.w);
            a0[4]=(short)f2bf(v1.x); a0[5]=(short)f2bf(v1.y); a0[6]=(short)f2bf(v1.z); a0[7]=(short)f2bf(v1.w);
            a1[0]=(short)f2bf(v2.x); a1[1]=(short)f2bf(v2.y); a1[2]=(short)f2bf(v2.z); a1[3]=(short)f2bf(v2.w);
            a1[4]=(short)f2bf(v3.x); a1[5]=(short)f2bf(v3.y); a1[6]=(short)f2bf(v3.z); a1[7]=(short)f2bf(v3.w);

            if (w == 0) {
                *reinterpret_cast<short8*>(hb + (size_t)nA * IN_F + (lg << 3)) = a0;
                *reinterpret_cast<short8*>(hb + (size_t)nA * IN_F + 32 + (lg << 3)) = a1;
            }

            f32x4 p1a = {0.f,0.f,0.f,0.f}, p2a = {0.f,0.f,0.f,0.f};
            p1a = __builtin_amdgcn_mfma_f32_16x16x32_bf16(a0, B1[0], p1a, 0, 0, 0);
            p1a = __builtin_amdgcn_mfma_f32_16x16x32_bf16(a1, B1[1], p1a, 0, 0, 0);
            p2a = __builtin_amdgcn_mfma_f32_16x16x32_bf16(a0, B2[0], p2a, 0, 0, 0);
            p2a = __builtin_amdgcn_mfma_f32_16x16x32_bf16(a1, B2[1], p2a, 0, 0, 0);

            #pragma unroll
            for (int rr = 0; rr < 4; ++rr) {
                int node = tile * 16 + (lg << 2) + rr;
                P1b[(size_t)node * IN_F + col] = f2bf(p1a[rr]);
                P2[(size_t)node * IN_F + col] = p2a[rr] + bj;
            }
        }
    } else {
        int cgid = (blockIdx.x - P12MM_BLKS) * 256 + tid;
        const float4* ef4 = reinterpret_cast<const float4*>(ef);
        #pragma unroll
        for (int k = 0; k < 5; ++k) {
            int i = cgid + k * (CONV_BLKS * 256);
            float4 v = ef4[i];
            ushort4 o;
            o.x = f2bf(v.x); o.y = f2bf(v.y); o.z = f2bf(v.z); o.w = f2bf(v.w);
            *reinterpret_cast<ushort4*>(efb + (size_t)i * 4) = o;
        }
        if (cgid < OUT_F * KTOT) {
            int n = cgid / KTOT, k = cgid % KTOT;
            WT[cgid] = f2bf(Wpost[(size_t)k * OUT_F + n]);
        }
        if (cgid < 64 * 16) {
            int n = cgid >> 4, k = cgid & 15;
            WefT[cgid] = f2bf(Wpre[(128 + k) * 64 + n]);
        }
    }
}

// ---------------- binC: counting-sort into BUCKET-STRIDED staging ----------------
__global__ __launch_bounds__(256) void binC_kernel(
    const int* __restrict__ src, const int* __restrict__ dst, int* __restrict__ bcur0,
    int* __restrict__ stage_e, int* __restrict__ stage_sd)
{
    __shared__ int sL[EPB_C];
    __shared__ int dL[EPB_C];
    __shared__ int bh[NB_BKT];
    __shared__ int bbase[NB_BKT];
    __shared__ int bcsr[NB_BKT];

    int tid = threadIdx.x;
    int e0 = blockIdx.x * EPB_C;

    bh[tid] = 0;
    __syncthreads();
    #pragma unroll
    for (int k = 0; k < EPB_C / 256; ++k) {
        int t = k * 256 + tid;
        int e = e0 + t;
        if (e < N_EDGES) {
            int s = src[e], d = dst[e];
            sL[t] = s; dL[t] = d;
            atomicAdd(&bh[d / NODES_PER_BKT], 1);
        }
    }
    __syncthreads();
    bbase[tid] = (bh[tid] > 0) ? atomicAdd(&bcur0[tid], bh[tid]) : 0;
    bcsr[tid] = 0;
    __syncthreads();
    #pragma unroll
    for (int k = 0; k < EPB_C / 256; ++k) {
        int t = k * 256 + tid;
        int e = e0 + t;
        if (e < N_EDGES) {
            int d = dL[t];
            int b = d / NODES_PER_BKT;
            int dl = d - b * NODES_PER_BKT;
            int r = atomicAdd(&bcsr[b], 1);
            int pos = (b << 12) + bbase[b] + r;     // bucket-strided
            stage_e[pos] = e;
            stage_sd[pos] = sL[t] | (dl << 16);
        }
    }
}

// ---------------- binD: per-bucket deg/row_start (LDS scan) + fine scatter ----------------
__global__ __launch_bounds__(256) void binD_kernel(
    const int* __restrict__ stage_e, const int* __restrict__ stage_sd,
    const int* __restrict__ bcur0,
    int* __restrict__ deg, int* __restrict__ row_start, int2* __restrict__ csr2)
{
    __shared__ int cnt[NB_BKT];
    __shared__ int lofs[NODES_PER_BKT];
    __shared__ int ws[4];
    int tid = threadIdx.x, lane = tid & 63, wv = tid >> 6;
    int b = blockIdx.x;
    int nb0 = b * NODES_PER_BKT;
    int base = b << 12;
    cnt[tid] = 0;
    __syncthreads();
    int cntb = bcur0[b];
    for (int p = base + tid; p < base + cntb; p += 256)
        atomicAdd(&cnt[stage_sd[p] >> 16], 1);
    __syncthreads();
    int v = cnt[tid];
    int sc = v;
    #pragma unroll
    for (int off = 1; off < 64; off <<= 1) {
        int u = __shfl_up(sc, off);
        if (lane >= off) sc += u;
    }
    if (lane == 63) ws[wv] = sc;
    __syncthreads();
    int wbase = 0;
    #pragma unroll
    for (int w = 0; w < 4; ++w) if (w < wv) wbase += ws[w];
    int ex = wbase + sc - v;
    if (tid < NODES_PER_BKT) {
        int n = nb0 + tid;
        if (n < N_NODES) { deg[n] = v; row_start[n] = base + ex; }
        lofs[tid] = base + ex;
    }
    __syncthreads();
    for (int p = base + tid; p < base + cntb; p += 256) {
        int sd = stage_sd[p];
        int r = atomicAdd(&lofs[sd >> 16], 1);
        csr2[r] = make_int2(stage_e[p], sd & 0xFFFF);
    }
}

// ---------------- aggregation via MFMA: 4 nodes per wave, full/tail tile split (R16 winner) ----------------
__global__ __launch_bounds__(256) void aggmm_kernel(
    const unsigned short* __restrict__ P1b, const float* __restrict__ P2,
    const unsigned short* __restrict__ efb, const unsigned short* __restrict__ WefT,
    const int2* __restrict__ csr2, const int* __restrict__ row_start,
    const int* __restrict__ deg, unsigned short* __restrict__ aggb)
{
    int tid = threadIdx.x;
    int lane = tid & 63;
    int lg = lane >> 4;
    int li = lane & 15;

    // fragments built once, reused across 4 nodes
    short8 bI0 = {}, bI1 = {};
    #pragma unroll
    for (int j = 0; j < 8; ++j) {
        int k_local = (lg << 3) + j;
        if (k_local == li)      bI0[j] = (short)0x3F80;
        if (k_local == 16 + li) bI1[j] = (short)0x3F80;
    }
    short8 bE[4];
    #pragma unroll
    for (int ct = 0; ct < 4; ++ct) {
        short8 b = {};
        if (lane < 32)
            b = *reinterpret_cast<const short8*>(WefT + (size_t)(ct * 16 + li) * 16 + (lg << 3));
        bE[ct] = b;
    }

    int wgid = rfl(blockIdx.x * 4 + (tid >> 6));    // 0..12499

    #pragma unroll 1
    for (int nn = 0; nn < 4; ++nn) {
        int n = wgid + nn * AGG_WAVES;              // < 50000 always
        int rs = rfl(row_start[n]);
        int dg = rfl(deg[n]);
        size_t obase = (size_t)n * AGG_F + lane;

        if (dg == 0) {
            aggb[obase] = 0; aggb[obase + 64] = 0;
            aggb[obase + 128] = 0; aggb[obase + 192] = 0;
            continue;
        }

        float p2n = P2[(size_t)n * IN_F + lane];
        const float NINF = -__builtin_inff(), PINF = __builtin_inff();
        float sm[4] = {0.f, 0.f, 0.f, 0.f};
        float sq[4] = {0.f, 0.f, 0.f, 0.f};
        float mx[4] = {NINF, NINF, NINF, NINF};
        float mn[4] = {PINF, PINF, PINF, PINF};

        for (int base = 0; base < dg; base += 64) {
            int cnt = dg - base; if (cnt > 64) cnt = 64;
            int2 es = make_int2(0, 0);
            if (lane < cnt) es = csr2[rs + base + lane];
            int eid = es.x, sid = es.y;
            int nfull = cnt >> 4;

            // ---- full tiles: no masks, no clamp ----
            for (int rt = 0; rt < nfull; ++rt) {
                int srcidx = rt * 16 + li;
                int s_l = __shfl(sid, srcidx);
                int e_l = __shfl(eid, srcidx);
                short8 aP0 = *reinterpret_cast<const short8*>(P1b + (size_t)s_l * IN_F + (lg << 3));
                short8 aP1 = *reinterpret_cast<const short8*>(P1b + (size_t)s_l * IN_F + 32 + (lg << 3));
                short8 aE = {};
                if (lane < 32)
                    aE = *reinterpret_cast<const short8*>(efb + (size_t)e_l * ED_F + (lg << 3));

                f32x4 c0 = {0.f,0.f,0.f,0.f}, c1 = {0.f,0.f,0.f,0.f};
                f32x4 c2 = {0.f,0.f,0.f,0.f}, c3 = {0.f,0.f,0.f,0.f};
                c0 = __builtin_amdgcn_mfma_f32_16x16x32_bf16(aP0, bI0, c0, 0, 0, 0);
                c1 = __builtin_amdgcn_mfma_f32_16x16x32_bf16(aP0, bI1, c1, 0, 0, 0);
                c2 = __builtin_amdgcn_mfma_f32_16x16x32_bf16(aP1, bI0, c2, 0, 0, 0);
                c3 = __builtin_amdgcn_mfma_f32_16x16x32_bf16(aP1, bI1, c3, 0, 0, 0);
                c0 = __builtin_amdgcn_mfma_f32_16x16x32_bf16(aE, bE[0], c0, 0, 0, 0);
                c1 = __builtin_amdgcn_mfma_f32_16x16x32_bf16(aE, bE[1], c1, 0, 0, 0);
                c2 = __builtin_amdgcn_mfma_f32_16x16x32_bf16(aE, bE[2], c2, 0, 0, 0);
                c3 = __builtin_amdgcn_mfma_f32_16x16x32_bf16(aE, bE[3], c3, 0, 0, 0);

                #pragma unroll
                for (int rr = 0; rr < 4; ++rr) {
                    float x0 = c0[rr], x1 = c1[rr], x2 = c2[rr], x3 = c3[rr];
                    sm[0] += x0; sm[1] += x1; sm[2] += x2; sm[3] += x3;
                    sq[0] = fmaf(x0, x0, sq[0]); sq[1] = fmaf(x1, x1, sq[1]);
                    sq[2] = fmaf(x2, x2, sq[2]); sq[3] = fmaf(x3, x3, sq[3]);
                    mx[0] = fmaxf(mx[0], x0); mx[1] = fmaxf(mx[1], x1);
                    mx[2] = fmaxf(mx[2], x2); mx[3] = fmaxf(mx[3], x3);
                    mn[0] = fminf(mn[0], x0); mn[1] = fminf(mn[1], x1);
                    mn[2] = fminf(mn[2], x2); mn[3] = fminf(mn[3], x3);
                }
            }

            // ---- tail tile: dup-pad (max/min neutral), mask sum/ssq ----
            if (cnt & 15) {
                int rowb0 = nfull * 16;
                int srcidx = rowb0 + li;
                if (srcidx >= cnt) srcidx = cnt - 1;
                int s_l = __shfl(sid, srcidx);
                int e_l = __shfl(eid, srcidx);
                short8 aP0 = *reinterpret_cast<const short8*>(P1b + (size_t)s_l * IN_F + (lg << 3));
                short8 aP1 = *reinterpret_cast<const short8*>(P1b + (size_t)s_l * IN_F + 32 + (lg << 3));
                short8 aE = {};
                if (lane < 32)
                    aE = *reinterpret_cast<const short8*>(efb + (size_t)e_l * ED_F + (lg << 3));

                f32x4 c0 = {0.f,0.f,0.f,0.f}, c1 = {0.f,0.f,0.f,0.f};
                f32x4 c2 = {0.f,0.f,0.f,0.f}, c3 = {0.f,0.f,0.f,0.f};
                c0 = __builtin_amdgcn_mfma_f32_16x16x32_bf16(aP0, bI0, c0, 0, 0, 0);
                c1 = __builtin_amdgcn_mfma_f32_16x16x32_bf16(aP0, bI1, c1, 0, 0, 0);
                c2 = __builtin_amdgcn_mfma_f32_16x16x32_bf16(aP1, bI0, c2, 0, 0, 0);
                c3 = __builtin_amdgcn_mfma_f32_16x16x32_bf16(aP1, bI1, c3, 0, 0, 0);
                c0 = __builtin_amdgcn_mfma_f32_16x16x32_bf16(aE, bE[0], c0, 0, 0, 0);
                c1 = __builtin_amdgcn_mfma_f32_16x16x32_bf16(aE, bE[1], c1, 0, 0, 0);
                c2 = __builtin_amdgcn_mfma_f32_16x16x32_bf16(aE, bE[2], c2, 0, 0, 0);
                c3 = __builtin_amdgcn_mfma_f32_16x16x32_bf16(aE, bE[3], c3, 0, 0, 0);

                int rb = rowb0 + (lg << 2);
                #pragma unroll
                for (int rr = 0; rr < 4; ++rr) {
                    bool vv = (rb + rr) < cnt;
                    float x0 = c0[rr], x1 = c1[rr], x2 = c2[rr], x3 = c3[rr];
                    float z0 = vv ? x0 : 0.f, z1 = vv ? x1 : 0.f, z2 = vv ? x2 : 0.f, z3 = vv ? x3 : 0.f;
                    sm[0] += z0; sm[1] += z1; sm[2] += z2; sm[3] += z3;
                    sq[0] = fmaf(z0, z0, sq[0]); sq[1] = fmaf(z1, z1, sq[1]);
                    sq[2] = fmaf(z2, z2, sq[2]); sq[3] = fmaf(z3, z3, sq[3]);
                    mx[0] = fmaxf(mx[0], x0); mx[1] = fmaxf(mx[1], x1);
                    mx[2] = fmaxf(mx[2], x2); mx[3] = fmaxf(mx[3], x3);
                    mn[0] = fminf(mn[0], x0); mn[1] = fminf(mn[1], x1);
                    mn[2] = fminf(mn[2], x2); mn[3] = fminf(mn[3], x3);
                }
            }
        }

        // butterfly over lane groups
        #pragma unroll
        for (int ct = 0; ct < 4; ++ct) {
            #pragma unroll
            for (int off = 16; off <= 32; off <<= 1) {
                sm[ct] += __shfl_xor(sm[ct], off);
                sq[ct] += __shfl_xor(sq[ct], off);
                mx[ct] = fmaxf(mx[ct], __shfl_xor(mx[ct], off));
                mn[ct] = fminf(mn[ct], __shfl_xor(mn[ct], off));
            }
        }
        bool s16 = (lane & 16) != 0, s32 = (lane & 32) != 0;
        float S  = s32 ? (s16 ? sm[3] : sm[2]) : (s16 ? sm[1] : sm[0]);
        float Qq = s32 ? (s16 ? sq[3] : sq[2]) : (s16 ? sq[1] : sq[0]);
        float MX = s32 ? (s16 ? mx[3] : mx[2]) : (s16 ? mx[1] : mx[0]);
        float MN = s32 ? (s16 ? mn[3] : mn[2]) : (s16 ? mn[1] : mn[0]);

        float degc = (float)dg;
        float mean_x = S / degc;
        float sd = sqrtf(fmaxf(Qq / degc - mean_x * mean_x, 0.f) + EPS_F);
        aggb[obase]       = f2bf(mean_x + p2n);
        aggb[obase + 64]  = f2bf(MX + p2n);
        aggb[obase + 128] = f2bf(MN + p2n);
        aggb[obase + 192] = f2bf(sd);
    }
}

// ---------------- MFMA post, persistent-B (unchanged R12) ----------------
constexpr int POST_BLOCKS = 625;
constexpr int TILES_PER_BLOCK = 5;
__global__ __launch_bounds__(256, 2) void postmm_kernel(
    const unsigned short* __restrict__ hb, const float* __restrict__ snorm,
    const unsigned short* __restrict__ WT, const float* __restrict__ bpost,
    const unsigned short* __restrict__ aggb, const int* __restrict__ deg,
    float* __restrict__ out)
{
    int tid = threadIdx.x;
    int lane = tid & 63;
    int li = lane & 15;
    int lg = lane >> 4;
    int w = tid >> 6;

    const unsigned short* Brow = WT + (size_t)(w * 16 + li) * KTOT + (lg << 3);
    short8 B[26];
    #pragma unroll
    for (int s = 0; s < 26; ++s)
        B[s] = *reinterpret_cast<const short8*>(Brow + s * 32);

    float bp = bpost[w * 16 + li];

    #pragma unroll 1
    for (int t = 0; t < TILES_PER_BLOCK; ++t) {
        int tile = blockIdx.x + t * POST_BLOCKS;
        int nA = tile * 16 + li;
        const unsigned short* Ah = hb + (size_t)nA * IN_F + (lg << 3);
        const unsigned short* Ag = aggb + (size_t)nA * AGG_F + (lg << 3);

        short8 ah0 = *reinterpret_cast<const short8*>(Ah);
        short8 ah1 = *reinterpret_cast<const short8*>(Ah + 32);
        short8 ag[8];
        #pragma unroll
        for (int s = 0; s < 8; ++s)
            ag[s] = *reinterpret_cast<const short8*>(Ag + s * 32);

        f32x4 accA = {0.f,0.f,0.f,0.f}, accB = {0.f,0.f,0.f,0.f}, accC = {0.f,0.f,0.f,0.f};
        accA = __builtin_amdgcn_mfma_f32_16x16x32_bf16(ah0, B[0], accA, 0, 0, 0);
        accA = __builtin_amdgcn_mfma_f32_16x16x32_bf16(ah1, B[1], accA, 0, 0, 0);
        #pragma unroll
        for (int s = 0; s < 8; ++s) {
            accA = __builtin_amdgcn_mfma_f32_16x16x32_bf16(ag[s], B[2 + s],  accA, 0, 0, 0);
            accB = __builtin_amdgcn_mfma_f32_16x16x32_bf16(ag[s], B[10 + s], accB, 0, 0, 0);
            accC = __builtin_amdgcn_mfma_f32_16x16x32_bf16(ag[s], B[18 + s], accC, 0, 0, 0);
        }

        #pragma unroll
        for (int rr = 0; rr < 4; ++rr) {
            int node = tile * 16 + (lg << 2) + rr;
            int dg = deg[node];
            float degc = fmaxf((float)dg, 1.f);
            float logd = logf(degc + 1.f);
            float aR = logd * (1.f / AVG_D_LOG_F);
            float bR = AVG_D_LOG_F / logd;
            float v = accA[rr] + aR * accB[rr] + bR * accC[rr] + bp;
            out[(size_t)node * OUT_F + w * 16 + li] = v * snorm[node];
        }
    }
}

extern "C" void kernel_launch(void* const* d_in, const int* in_sizes, int n_in,
                              void* d_out, int out_size, void* d_ws, size_t ws_size,
                              hipStream_t stream) {
    const float* h     = (const float*)d_in[0];
    const float* ef    = (const float*)d_in[1];
    const float* snorm = (const float*)d_in[2];
    const float* Wpre  = (const float*)d_in[3];
    const float* bpre  = (const float*)d_in[4];
    const float* Wpost = (const float*)d_in[5];
    const float* bpost = (const float*)d_in[6];
    const int* src     = (const int*)d_in[7];
    const int* dst     = (const int*)d_in[8];
    float* out = (float*)d_out;

    char* ws = (char*)d_ws;
    size_t off = 0;
    auto alloc = [&](size_t bytes) { char* p = ws + off; off += (bytes + 255) & ~size_t(255); return p; };
    unsigned short* P1b  = (unsigned short*)alloc((size_t)N_NODES * IN_F * 2);
    float* P2            = (float*)alloc((size_t)N_NODES * IN_F * 4);
    unsigned short* hb   = (unsigned short*)alloc((size_t)N_NODES * IN_F * 2);
    unsigned short* aggb = (unsigned short*)alloc((size_t)N_NODES * AGG_F * 2);
    unsigned short* efb  = (unsigned short*)alloc((size_t)N_EDGES * ED_F * 2);
    int* deg       = (int*)alloc((size_t)N_NODES * 4);
    int* row_start = (int*)alloc((size_t)N_NODES * 4);
    int2* csr2     = (int2*)alloc((size_t)NB_BKT * BKT_STRIDE * 8);
    int* stage_e   = (int*)alloc((size_t)NB_BKT * BKT_STRIDE * 4);
    int* stage_sd  = (int*)alloc((size_t)NB_BKT * BKT_STRIDE * 4);
    int* bcur0     = (int*)alloc((size_t)NB_BKT * 4);
    unsigned short* WT   = (unsigned short*)alloc((size_t)OUT_F * KTOT * 2);
    unsigned short* WefT = (unsigned short*)alloc((size_t)64 * 16 * 2);

    hipMemsetAsync(bcur0, 0, (size_t)NB_BKT * 4, stream);
    hipLaunchKernelGGL(prep_kernel, dim3(P12MM_BLKS + CONV_BLKS), dim3(256), 0, stream,
                       h, Wpre, bpre, ef, Wpost,
                       P1b, P2, hb, efb, WT, WefT);
    hipLaunchKernelGGL(binC_kernel, dim3(NBLK_C), dim3(256), 0, stream,
                       src, dst, bcur0, stage_e, stage_sd);
    hipLaunchKernelGGL(binD_kernel, dim3(NB_BKT), dim3(256), 0, stream,
                       stage_e, stage_sd, bcur0, deg, row_start, csr2);
    hipLaunchKernelGGL(aggmm_kernel, dim3(AGG_BLOCKS), dim3(256), 0, stream,
                       P1b, P2, efb, WefT, csr2, row_start, deg, aggb);
    hipLaunchKernelGGL(postmm_kernel, dim3(POST_BLOCKS), dim3(256), 0, stream,
                       hb, snorm, WT, bpost, aggb, deg, out);
}